// Round 16
// baseline (75.261 us; speedup 1.0000x reference)
//
#include <hip/hip_runtime.h>

#define NSUB   10000
#define NCLS   17
#define NG     500
#define NE     80000
#define HIDN   8
#define NEG_SLOPE 0.2f

typedef __attribute__((ext_vector_type(8))) short short8;
typedef __attribute__((ext_vector_type(4))) float f32x4;

// ws layout (float units)
#define OFF_B1   0                        // 512x64 bf16 = 16384 float slots
#define OFF_B2   16384                    // 512x32 bf16 = 8192 float slots
#define OFF_D    (OFF_B2 + 8192)          // 32
#define OFF_SP   (OFF_D + 32)             // NSUB*32: {xl[8], P[17], 0 x7} per node
#define OFF_DP   (OFF_SP + NSUB*32)       // NSUB*32: {xr[8], logP[17], 0 x7} per node
#define OFF_NUM  (OFF_DP + NSUB*32)       // NSUB
#define OFF_DEN  (OFF_NUM + NSUB)         // NSUB
// measurement scratch (dummy k_cell instances)
#define OFF_SP2  (OFF_DEN + NSUB)         // NSUB*32
#define OFF_DP2  (OFF_SP2 + NSUB*32)      // NSUB*32
#define OFF_OUT2 (OFF_DP2 + NSUB*32)      // 2 + NSUB*17

__device__ __forceinline__ unsigned short f2bf(float f) {
    unsigned u = __float_as_uint(f);
    u += 0x7FFFu + ((u >> 16) & 1u);      // round-to-nearest-even
    return (unsigned short)(u >> 16);
}

#define MFMA16 __builtin_amdgcn_mfma_f32_16x16x32_bf16

// ---- prep v2 (round-14, measured good): 16-block LDS-staged fragment build ----
__global__ void k_prep(const float* __restrict__ Mu, const float* __restrict__ Var,
                       const float* __restrict__ Wl, const float* __restrict__ Wr,
                       unsigned short* __restrict__ B1, unsigned short* __restrict__ B2,
                       float* __restrict__ D, float* __restrict__ zeroBase,
                       float* __restrict__ out) {
    const int b = blockIdx.x;
    const int tid = threadIdx.x;
    if (b < 16) {
        const int ks = b;
        __shared__ float sMu[NCLS][33], sVa[NCLS][33];
        __shared__ float sWl[32][8], sWr[32][8];
        for (int t = tid; t < NCLS * 32; t += 256) {
            const int c = t >> 5, gg = t & 31;
            const int g = ks * 32 + gg;
            sMu[c][gg] = (g < NG) ? Mu[c * NG + g] : 0.f;
            sVa[c][gg] = (g < NG) ? Var[c * NG + g] : 1.f;
        }
        {
            const int gg = tid >> 3, h = tid & 7;
            const int g = ks * 32 + gg;
            sWl[gg][h] = (g < NG) ? Wl[g * HIDN + h] : 0.f;
            sWr[gg][h] = (g < NG) ? Wr[g * HIDN + h] : 0.f;
        }
        __syncthreads();
        if (tid < 64) {
            const int lane = tid;
            const int fgrp = lane >> 4, fj = lane & 15;
            unsigned short v1[4][8], v2[2][8];
            #pragma unroll
            for (int e = 0; e < 8; e++) {
                const int gg = fgrp * 8 + e;
                const bool gv = (ks * 32 + gg < NG);
                #pragma unroll
                for (int nt = 0; nt < 4; nt++) {
                    const int col = nt * 16 + fj;
                    float v = 0.f;
                    if (gv) {
                        if (col >= 17 && col < 34)      v = sMu[col - 17][gg] / sVa[col - 17][gg];
                        else if (col >= 34 && col < 42) v = sWl[gg][col - 34];
                        else if (col >= 42 && col < 50) v = sWr[gg][col - 42];
                    }
                    v1[nt][e] = f2bf(v);
                }
                #pragma unroll
                for (int nt = 0; nt < 2; nt++) {
                    const int col = nt * 16 + fj;
                    float v = 0.f;
                    if (gv && col < NCLS) v = 1.0f / sVa[col][gg];
                    v2[nt][e] = f2bf(v);
                }
            }
            #pragma unroll
            for (int nt = 0; nt < 4; nt++)
                *reinterpret_cast<short8*>(B1 + (size_t)((ks * 4 + nt) * 64 + lane) * 8) =
                    *reinterpret_cast<short8*>(v1[nt]);
            #pragma unroll
            for (int nt = 0; nt < 2; nt++)
                *reinterpret_cast<short8*>(B2 + (size_t)((ks * 2 + nt) * 64 + lane) * 8) =
                    *reinterpret_cast<short8*>(v2[nt]);
        }
    } else if (b < 33) {
        const int c = b - 16;
        float s = 0.f;
        for (int g = tid; g < NG; g += 256) {
            const float m = Mu[c * NG + g];
            s += m * m / Var[c * NG + g];
        }
        __shared__ float red[4];
        #pragma unroll
        for (int o = 32; o; o >>= 1) s += __shfl_xor(s, o);
        const int w = tid >> 6, l = tid & 63;
        if (l == 0) red[w] = s;
        __syncthreads();
        if (tid == 0) D[c] = red[0] + red[1] + red[2] + red[3];
    } else {
        const int i = (b - 33) * 256 + tid;           // zero NUM/DEN (2*NSUB)
        if (i < 2 * NSUB) zeroBase[i] = 0.f;
        if (b == 33 && tid < 2) out[tid] = 0.f;
    }
}

// ---- per-cell: MFMA GEMM, round-9/14 structure (measured best) ----
__launch_bounds__(256)
__global__ void k_cell(const float* __restrict__ x, const int* __restrict__ sidx,
                       const float* __restrict__ Wp, const float* __restrict__ Sp,
                       const float* __restrict__ blv, const float* __restrict__ brv,
                       const unsigned short* __restrict__ B1,
                       const unsigned short* __restrict__ B2,
                       const float* __restrict__ D,
                       float* __restrict__ out, float* __restrict__ SP,
                       float* __restrict__ DP) {
    const int tid = threadIdx.x;
    const int w = tid >> 6, l = tid & 63;
    const int grp = l >> 4, j = l & 15;
    const int rowbase = blockIdx.x * 16;             // 625 tiles exactly

    f32x4 a0 = {0,0,0,0}, a1 = {0,0,0,0}, a2 = {0,0,0,0}, a3 = {0,0,0,0};
    const float* xr = x + (size_t)(rowbase + j) * NG;
    const short8* b1 = reinterpret_cast<const short8*>(B1);
    const short8* b2 = reinterpret_cast<const short8*>(B2);

#define KSTEP(ks, fa, fb)                                                \
    {                                                                    \
        const short8* p1 = b1 + (size_t)((ks) * 4) * 64 + l;             \
        const short8* p2 = b2 + (size_t)((ks) * 2) * 64 + l;             \
        a0 = MFMA16(fa, p1[0],   a0, 0, 0, 0);                           \
        a1 = MFMA16(fa, p1[64],  a1, 0, 0, 0);                           \
        a2 = MFMA16(fa, p1[128], a2, 0, 0, 0);                           \
        a3 = MFMA16(fa, p1[192], a3, 0, 0, 0);                           \
        a0 = MFMA16(fb, p2[0],   a0, 0, 0, 0);                           \
        a1 = MFMA16(fb, p2[64],  a1, 0, 0, 0);                           \
    }

    const int ks0 = w * 4;
    #pragma unroll
    for (int i = 0; i < 3; i++) {
        const int ks = ks0 + i;
        const int g0 = ks * 32 + grp * 8;
        const float4 v0 = *reinterpret_cast<const float4*>(xr + g0);
        const float4 v1 = *reinterpret_cast<const float4*>(xr + g0 + 4);
        const float xv[8] = { v0.x, v0.y, v0.z, v0.w, v1.x, v1.y, v1.z, v1.w };
        short8 fa, fb;
        #pragma unroll
        for (int e = 0; e < 8; e++) { fa[e] = (short)f2bf(xv[e]); fb[e] = (short)f2bf(xv[e] * xv[e]); }
        KSTEP(ks, fa, fb);
    }
    if (w < 3) {
        const int ks = ks0 + 3;
        const int g0 = ks * 32 + grp * 8;
        const float4 v0 = *reinterpret_cast<const float4*>(xr + g0);
        const float4 v1 = *reinterpret_cast<const float4*>(xr + g0 + 4);
        const float xv[8] = { v0.x, v0.y, v0.z, v0.w, v1.x, v1.y, v1.z, v1.w };
        short8 fa, fb;
        #pragma unroll
        for (int e = 0; e < 8; e++) { fa[e] = (short)f2bf(xv[e]); fb[e] = (short)f2bf(xv[e] * xv[e]); }
        KSTEP(ks, fa, fb);
    } else {                                         // ks = 15 tail: genes 480..499 valid
        const int g0 = 480 + grp * 8;
        float4 v0 = {0,0,0,0}, v1 = {0,0,0,0};
        if (g0 <= 496) v0 = *reinterpret_cast<const float4*>(xr + g0);
        if (g0 <= 488) v1 = *reinterpret_cast<const float4*>(xr + g0 + 4);
        const float xv[8] = { v0.x, v0.y, v0.z, v0.w, v1.x, v1.y, v1.z, v1.w };
        short8 fa, fb;
        #pragma unroll
        for (int e = 0; e < 8; e++) { fa[e] = (short)f2bf(xv[e]); fb[e] = (short)f2bf(xv[e] * xv[e]); }
        KSTEP(15, fa, fb);
    }
#undef KSTEP

    // C layout: row = grp*4 + r, col = nt*16 + j (m89-verified)
    __shared__ float ct[4][16][68];
    #pragma unroll
    for (int r = 0; r < 4; r++) {
        ct[w][grp * 4 + r][j]      = a0[r];
        ct[w][grp * 4 + r][16 + j] = a1[r];
        ct[w][grp * 4 + r][32 + j] = a2[r];
        ct[w][grp * 4 + r][48 + j] = a3[r];
    }
    __syncthreads();

    if (w == 0) {
        float ll = 0.f;
        if (l < 16) {
            const int cell = rowbase + l;
            const int idx = sidx[cell];
            const float* wrow = Wp + (size_t)idx * NCLS;
            float p[NCLS];
            float mx = -1e30f;
            #pragma unroll
            for (int c = 0; c < NCLS; c++) { p[c] = wrow[c]; mx = fmaxf(mx, p[c]); }
            float sum = 0.f;
            #pragma unroll
            for (int c = 0; c < NCLS; c++) { p[c] = __expf(p[c] - mx); sum += p[c]; }
            const float inv = 1.0f / sum;
            const float s = Sp[idx];
            float* orow = out + 2 + (size_t)cell * NCLS;
            float* sp   = SP + (size_t)cell * 32;
            float* dp   = DP + (size_t)cell * 32;
            float ll_c = 0.f;
            #pragma unroll
            for (int c = 0; c < NCLS; c++) {
                p[c] *= inv;
                const float lg = __logf(p[c] + 1e-8f);
                orow[c]    = p[c];
                sp[8 + c]  = p[c];
                dp[8 + c]  = lg;
                const float T1 = ct[0][l][c] + ct[1][l][c] + ct[2][l][c] + ct[3][l][c];
                const float T2 = ct[0][l][NCLS + c] + ct[1][l][NCLS + c]
                               + ct[2][l][NCLS + c] + ct[3][l][NCLS + c];
                ll_c += p[c] * (-0.5f * T1 + s * T2 - 0.5f * s * s * D[c]);
            }
            ll = ll_c;
            #pragma unroll
            for (int q = 25; q < 32; q++) { sp[q] = 0.f; dp[q] = 0.f; }
            #pragma unroll
            for (int h = 0; h < HIDN; h++) {
                sp[h] = ct[0][l][34 + h] + ct[1][l][34 + h]
                      + ct[2][l][34 + h] + ct[3][l][34 + h] + blv[h];
                dp[h] = ct[0][l][42 + h] + ct[1][l][42 + h]
                      + ct[2][l][42 + h] + ct[3][l][42 + h] + brv[h];
            }
        }
        #pragma unroll
        for (int o = 32; o; o >>= 1) ll += __shfl_xor(ll, o);
        if (l == 0) atomicAdd(out, ll * (1.0f / NSUB));
    }
}

// ---- fused edge pass: 2-line packed gathers per side, no max-shift ----
__global__ void k_edge(const int* __restrict__ ei, const float* __restrict__ att,
                       const float* __restrict__ SP, const float* __restrict__ DP,
                       float* __restrict__ NUM, float* __restrict__ DEN) {
    const int k = blockIdx.x * 256 + threadIdx.x;
    if (k >= NE) return;
    const int s = ei[k], d = ei[NE + k];
    const float4* sp = reinterpret_cast<const float4*>(SP + (size_t)s * 32);
    const float4* dp = reinterpret_cast<const float4*>(DP + (size_t)d * 32);
    const float4 xa0 = sp[0], xa1 = sp[1];
    const float4 xb0 = dp[0], xb1 = dp[1];
    const float hv[8] = { xa0.x + xb0.x, xa0.y + xb0.y, xa0.z + xb0.z, xa0.w + xb0.w,
                          xa1.x + xb1.x, xa1.y + xb1.y, xa1.z + xb1.z, xa1.w + xb1.w };
    float e = 0.f;
    #pragma unroll
    for (int h = 0; h < HIDN; h++) {
        const float v = hv[h];
        e += ((v > 0.f) ? v : NEG_SLOPE * v) * att[h];
    }
    const float ex = __expf(e);            // no max-shift: |e| <~ 8, exp in f32 range
    float wgt = 0.f;
    #pragma unroll
    for (int q = 2; q < 7; q++) {          // P[17]+pad dot logP[17]+pad
        const float4 ps = sp[q];
        const float4 ld = dp[q];
        wgt += ps.x * ld.x + ps.y * ld.y + ps.z * ld.z + ps.w * ld.w;
    }
    atomicAdd(NUM + d, ex * wgt);
    atomicAdd(DEN + d, ex);
}

// ---- node pass: ce_space = -sum(num/den)/n ----
__global__ void k_node(const float* __restrict__ NUM, const float* __restrict__ DEN,
                       float* __restrict__ out) {
    const int n = blockIdx.x * 256 + threadIdx.x;
    float v = 0.f;
    if (n < NSUB) {
        const float dd = DEN[n];
        if (dd > 0.f) v = NUM[n] / dd;
    }
    #pragma unroll
    for (int o = 32; o; o >>= 1) v += __shfl_xor(v, o);
    if ((threadIdx.x & 63) == 0 && v != 0.f) atomicAdd(out + 1, -v * (1.0f / NSUB));
}

extern "C" void kernel_launch(void* const* d_in, const int* in_sizes, int n_in,
                              void* d_out, int out_size, void* d_ws, size_t ws_size,
                              hipStream_t stream) {
    const float* x    = (const float*)d_in[0];
    const float* Mu   = (const float*)d_in[1];
    const float* Var  = (const float*)d_in[2];
    const int*   ei   = (const int*)d_in[3];
    const int*   sidx = (const int*)d_in[4];
    const float* Wp   = (const float*)d_in[5];
    const float* Sp   = (const float*)d_in[6];
    const float* Wl   = (const float*)d_in[7];
    const float* bl   = (const float*)d_in[8];
    const float* Wr   = (const float*)d_in[9];
    const float* br   = (const float*)d_in[10];
    const float* att  = (const float*)d_in[11];
    float* out = (float*)d_out;
    float* ws  = (float*)d_ws;

    unsigned short* B1 = (unsigned short*)(ws + OFF_B1);
    unsigned short* B2 = (unsigned short*)(ws + OFF_B2);
    float* D    = ws + OFF_D;
    float* SP   = ws + OFF_SP;
    float* DP   = ws + OFF_DP;
    float* NUM  = ws + OFF_NUM;
    float* DEN  = ws + OFF_DEN;
    float* SP2  = ws + OFF_SP2;
    float* DP2  = ws + OFF_DP2;
    float* OUT2 = ws + OFF_OUT2;

    (void)in_sizes; (void)n_in; (void)out_size; (void)ws_size;

    k_prep<<<112, 256, 0, stream>>>(Mu, Var, Wl, Wr, B1, B2, D, NUM, out);
    // MEASUREMENT: two dummy k_cell instances into scratch (first pays cold-L3,
    // second runs warm). delta(total) vs 45.4 = 2 x (warm_cell + gap).
    k_cell<<<NSUB / 16, 256, 0, stream>>>(x, sidx, Wp, Sp, bl, br, B1, B2, D,
                                          OUT2, SP2, DP2);
    k_cell<<<NSUB / 16, 256, 0, stream>>>(x, sidx, Wp, Sp, bl, br, B1, B2, D,
                                          OUT2, SP2, DP2);
    // real instance (unchanged outputs)
    k_cell<<<NSUB / 16, 256, 0, stream>>>(x, sidx, Wp, Sp, bl, br, B1, B2, D,
                                          out, SP, DP);
    k_edge<<<(NE + 255) / 256, 256, 0, stream>>>(ei, att, SP, DP, NUM, DEN);
    k_node<<<(NSUB + 255) / 256, 256, 0, stream>>>(NUM, DEN, out);
}

// Round 17
// 45.860 us; speedup vs baseline: 1.6411x; 1.6411x over previous
//
#include <hip/hip_runtime.h>

#define NSUB   10000
#define NCLS   17
#define NG     500
#define NE     80000
#define HIDN   8
#define NEG_SLOPE 0.2f

typedef __attribute__((ext_vector_type(8))) short short8;
typedef __attribute__((ext_vector_type(4))) float f32x4;

// ws layout (float units)
#define OFF_B1   0                        // 512x64 bf16 = 16384 float slots
#define OFF_B2   16384                    // 512x32 bf16 = 8192 float slots
#define OFF_D    (OFF_B2 + 8192)          // 32
#define OFF_SP   (OFF_D + 32)             // NSUB*32: {xl[8], P[17], 0 x7} per node
#define OFF_DP   (OFF_SP + NSUB*32)       // NSUB*32: {xr[8], logP[17], 0 x7} per node
#define OFF_NUM  (OFF_DP + NSUB*32)       // NSUB
#define OFF_DEN  (OFF_NUM + NSUB)         // NSUB

__device__ __forceinline__ unsigned short f2bf(float f) {
    unsigned u = __float_as_uint(f);
    u += 0x7FFFu + ((u >> 16) & 1u);      // round-to-nearest-even
    return (unsigned short)(u >> 16);
}

#define MFMA16 __builtin_amdgcn_mfma_f32_16x16x32_bf16

// ---- prep v2 (round-14, measured good): 16-block LDS-staged fragment build ----
__global__ void k_prep(const float* __restrict__ Mu, const float* __restrict__ Var,
                       const float* __restrict__ Wl, const float* __restrict__ Wr,
                       unsigned short* __restrict__ B1, unsigned short* __restrict__ B2,
                       float* __restrict__ D, float* __restrict__ zeroBase,
                       float* __restrict__ out) {
    const int b = blockIdx.x;
    const int tid = threadIdx.x;
    if (b < 16) {
        const int ks = b;
        __shared__ float sMu[NCLS][33], sVa[NCLS][33];
        __shared__ float sWl[32][8], sWr[32][8];
        for (int t = tid; t < NCLS * 32; t += 256) {
            const int c = t >> 5, gg = t & 31;
            const int g = ks * 32 + gg;
            sMu[c][gg] = (g < NG) ? Mu[c * NG + g] : 0.f;
            sVa[c][gg] = (g < NG) ? Var[c * NG + g] : 1.f;
        }
        {
            const int gg = tid >> 3, h = tid & 7;
            const int g = ks * 32 + gg;
            sWl[gg][h] = (g < NG) ? Wl[g * HIDN + h] : 0.f;
            sWr[gg][h] = (g < NG) ? Wr[g * HIDN + h] : 0.f;
        }
        __syncthreads();
        if (tid < 64) {
            const int lane = tid;
            const int fgrp = lane >> 4, fj = lane & 15;
            unsigned short v1[4][8], v2[2][8];
            #pragma unroll
            for (int e = 0; e < 8; e++) {
                const int gg = fgrp * 8 + e;
                const bool gv = (ks * 32 + gg < NG);
                #pragma unroll
                for (int nt = 0; nt < 4; nt++) {
                    const int col = nt * 16 + fj;
                    float v = 0.f;
                    if (gv) {
                        if (col >= 17 && col < 34)      v = sMu[col - 17][gg] / sVa[col - 17][gg];
                        else if (col >= 34 && col < 42) v = sWl[gg][col - 34];
                        else if (col >= 42 && col < 50) v = sWr[gg][col - 42];
                    }
                    v1[nt][e] = f2bf(v);
                }
                #pragma unroll
                for (int nt = 0; nt < 2; nt++) {
                    const int col = nt * 16 + fj;
                    float v = 0.f;
                    if (gv && col < NCLS) v = 1.0f / sVa[col][gg];
                    v2[nt][e] = f2bf(v);
                }
            }
            #pragma unroll
            for (int nt = 0; nt < 4; nt++)
                *reinterpret_cast<short8*>(B1 + (size_t)((ks * 4 + nt) * 64 + lane) * 8) =
                    *reinterpret_cast<short8*>(v1[nt]);
            #pragma unroll
            for (int nt = 0; nt < 2; nt++)
                *reinterpret_cast<short8*>(B2 + (size_t)((ks * 2 + nt) * 64 + lane) * 8) =
                    *reinterpret_cast<short8*>(v2[nt]);
        }
    } else if (b < 33) {
        const int c = b - 16;
        float s = 0.f;
        for (int g = tid; g < NG; g += 256) {
            const float m = Mu[c * NG + g];
            s += m * m / Var[c * NG + g];
        }
        __shared__ float red[4];
        #pragma unroll
        for (int o = 32; o; o >>= 1) s += __shfl_xor(s, o);
        const int w = tid >> 6, l = tid & 63;
        if (l == 0) red[w] = s;
        __syncthreads();
        if (tid == 0) D[c] = red[0] + red[1] + red[2] + red[3];
    } else {
        const int i = (b - 33) * 256 + tid;           // zero NUM/DEN (2*NSUB)
        if (i < 2 * NSUB) zeroBase[i] = 0.f;
        if (b == 33 && tid < 2) out[tid] = 0.f;
    }
}

// ---- per-cell: MFMA GEMM with LINEAR-streamed async LDS staging of x ----
// The block's 16 rows are CONTIGUOUS in memory (32 KB). Stage with idx linear
// in both src and dest: lane-consecutive 16B -> perfect coalescing (4 KB/wave
// instr), fixing the 2KB-stride 16B-scatter that made x reads granularity-
// bound (round-16 measurement: cold cell ~22 us, warm ~12 us, floor 3.2 us).
// LDS holds all 500 genes/row; kstep reads sx4[j*125 + c4] (8-way bank
// conflict but only 32 reads/block -> negligible).
__launch_bounds__(256)
__global__ void k_cell(const float* __restrict__ x, const int* __restrict__ sidx,
                       const float* __restrict__ Wp, const float* __restrict__ Sp,
                       const float* __restrict__ blv, const float* __restrict__ brv,
                       const unsigned short* __restrict__ B1,
                       const unsigned short* __restrict__ B2,
                       const float* __restrict__ D,
                       float* __restrict__ out, float* __restrict__ SP,
                       float* __restrict__ DP) {
    const int tid = threadIdx.x;
    const int w = tid >> 6, l = tid & 63;
    const int grp = l >> 4, j = l & 15;
    const int rowbase = blockIdx.x * 16;             // 625 tiles exactly

    __shared__ float4 sx4[2000];                     // 32 KB: 16 rows x 125 float4
    {
        const float4* xbase4 = reinterpret_cast<const float4*>(x + (size_t)rowbase * NG);
        #pragma unroll
        for (int r = 0; r < 8; r++) {
            const int idx = r * 256 + tid;
            if (idx < 2000) {
                __builtin_amdgcn_global_load_lds(
                    (const __attribute__((address_space(1))) void*)(xbase4 + idx),
                    (__attribute__((address_space(3))) void*)&sx4[idx],
                    16, 0, 0);
            }
        }
    }

    const short8* b1 = reinterpret_cast<const short8*>(B1);
    const short8* b2 = reinterpret_cast<const short8*>(B2);
    f32x4 a0 = {0,0,0,0}, a1 = {0,0,0,0}, a2 = {0,0,0,0}, a3 = {0,0,0,0};

    __syncthreads();                                 // staging complete

#define KSTEP(ks, fa, fb)                                                \
    {                                                                    \
        const short8* p1 = b1 + (size_t)((ks) * 4) * 64 + l;             \
        const short8* p2 = b2 + (size_t)((ks) * 2) * 64 + l;             \
        a0 = MFMA16(fa, p1[0],   a0, 0, 0, 0);                           \
        a1 = MFMA16(fa, p1[64],  a1, 0, 0, 0);                           \
        a2 = MFMA16(fa, p1[128], a2, 0, 0, 0);                           \
        a3 = MFMA16(fa, p1[192], a3, 0, 0, 0);                           \
        a0 = MFMA16(fb, p2[0],   a0, 0, 0, 0);                           \
        a1 = MFMA16(fb, p2[64],  a1, 0, 0, 0);                           \
    }
#define KSTEP_L(ks)                                                      \
    {                                                                    \
        const int c4 = (ks) * 8 + grp * 2;                               \
        const float4 v0 = sx4[j * 125 + c4];                             \
        const float4 v1 = sx4[j * 125 + c4 + 1];                         \
        const float xv[8] = { v0.x, v0.y, v0.z, v0.w,                    \
                              v1.x, v1.y, v1.z, v1.w };                  \
        short8 fa, fb;                                                   \
        _Pragma("unroll")                                                \
        for (int e = 0; e < 8; e++) {                                    \
            fa[e] = (short)f2bf(xv[e]);                                  \
            fb[e] = (short)f2bf(xv[e] * xv[e]);                          \
        }                                                                \
        KSTEP(ks, fa, fb);                                               \
    }

    const int ks0 = w * 4;
    KSTEP_L(ks0 + 0)
    KSTEP_L(ks0 + 1)
    KSTEP_L(ks0 + 2)
    if (w < 3) {
        KSTEP_L(ks0 + 3)
    } else {                                         // ks = 15: genes 480..499 (c4 120..124)
        const int c4 = 120 + grp * 2;
        const float4 z = {0.f, 0.f, 0.f, 0.f};
        const float4 v0 = (c4     <= 124) ? sx4[j * 125 + c4]     : z;
        const float4 v1 = (c4 + 1 <= 124) ? sx4[j * 125 + c4 + 1] : z;
        const float xv[8] = { v0.x, v0.y, v0.z, v0.w, v1.x, v1.y, v1.z, v1.w };
        short8 fa, fb;
        #pragma unroll
        for (int e = 0; e < 8; e++) { fa[e] = (short)f2bf(xv[e]); fb[e] = (short)f2bf(xv[e] * xv[e]); }
        KSTEP(15, fa, fb);
    }
#undef KSTEP_L
#undef KSTEP

    // C layout: row = grp*4 + r, col = nt*16 + j (m89-verified)
    __shared__ float ct[4][16][68];
    #pragma unroll
    for (int r = 0; r < 4; r++) {
        ct[w][grp * 4 + r][j]      = a0[r];
        ct[w][grp * 4 + r][16 + j] = a1[r];
        ct[w][grp * 4 + r][32 + j] = a2[r];
        ct[w][grp * 4 + r][48 + j] = a3[r];
    }
    __syncthreads();

    if (w == 0) {
        float ll = 0.f;
        if (l < 16) {
            const int cell = rowbase + l;
            const int idx = sidx[cell];
            const float* wrow = Wp + (size_t)idx * NCLS;
            float p[NCLS];
            float mx = -1e30f;
            #pragma unroll
            for (int c = 0; c < NCLS; c++) { p[c] = wrow[c]; mx = fmaxf(mx, p[c]); }
            float sum = 0.f;
            #pragma unroll
            for (int c = 0; c < NCLS; c++) { p[c] = __expf(p[c] - mx); sum += p[c]; }
            const float inv = 1.0f / sum;
            const float s = Sp[idx];
            float* orow = out + 2 + (size_t)cell * NCLS;
            float* sp   = SP + (size_t)cell * 32;
            float* dp   = DP + (size_t)cell * 32;
            float ll_c = 0.f;
            #pragma unroll
            for (int c = 0; c < NCLS; c++) {
                p[c] *= inv;
                const float lg = __logf(p[c] + 1e-8f);
                orow[c]    = p[c];
                sp[8 + c]  = p[c];
                dp[8 + c]  = lg;
                const float T1 = ct[0][l][c] + ct[1][l][c] + ct[2][l][c] + ct[3][l][c];
                const float T2 = ct[0][l][NCLS + c] + ct[1][l][NCLS + c]
                               + ct[2][l][NCLS + c] + ct[3][l][NCLS + c];
                ll_c += p[c] * (-0.5f * T1 + s * T2 - 0.5f * s * s * D[c]);
            }
            ll = ll_c;
            #pragma unroll
            for (int q = 25; q < 32; q++) { sp[q] = 0.f; dp[q] = 0.f; }
            #pragma unroll
            for (int h = 0; h < HIDN; h++) {
                sp[h] = ct[0][l][34 + h] + ct[1][l][34 + h]
                      + ct[2][l][34 + h] + ct[3][l][34 + h] + blv[h];
                dp[h] = ct[0][l][42 + h] + ct[1][l][42 + h]
                      + ct[2][l][42 + h] + ct[3][l][42 + h] + brv[h];
            }
        }
        #pragma unroll
        for (int o = 32; o; o >>= 1) ll += __shfl_xor(ll, o);
        if (l == 0) atomicAdd(out, ll * (1.0f / NSUB));
    }
}

// ---- fused edge pass: 2-line packed gathers per side, no max-shift ----
__global__ void k_edge(const int* __restrict__ ei, const float* __restrict__ att,
                       const float* __restrict__ SP, const float* __restrict__ DP,
                       float* __restrict__ NUM, float* __restrict__ DEN) {
    const int k = blockIdx.x * 256 + threadIdx.x;
    if (k >= NE) return;
    const int s = ei[k], d = ei[NE + k];
    const float4* sp = reinterpret_cast<const float4*>(SP + (size_t)s * 32);
    const float4* dp = reinterpret_cast<const float4*>(DP + (size_t)d * 32);
    const float4 xa0 = sp[0], xa1 = sp[1];
    const float4 xb0 = dp[0], xb1 = dp[1];
    const float hv[8] = { xa0.x + xb0.x, xa0.y + xb0.y, xa0.z + xb0.z, xa0.w + xb0.w,
                          xa1.x + xb1.x, xa1.y + xb1.y, xa1.z + xb1.z, xa1.w + xb1.w };
    float e = 0.f;
    #pragma unroll
    for (int h = 0; h < HIDN; h++) {
        const float v = hv[h];
        e += ((v > 0.f) ? v : NEG_SLOPE * v) * att[h];
    }
    const float ex = __expf(e);            // no max-shift: |e| <~ 8, exp in f32 range
    float wgt = 0.f;
    #pragma unroll
    for (int q = 2; q < 7; q++) {          // P[17]+pad dot logP[17]+pad
        const float4 ps = sp[q];
        const float4 ld = dp[q];
        wgt += ps.x * ld.x + ps.y * ld.y + ps.z * ld.z + ps.w * ld.w;
    }
    atomicAdd(NUM + d, ex * wgt);
    atomicAdd(DEN + d, ex);
}

// ---- node pass: ce_space = -sum(num/den)/n ----
__global__ void k_node(const float* __restrict__ NUM, const float* __restrict__ DEN,
                       float* __restrict__ out) {
    const int n = blockIdx.x * 256 + threadIdx.x;
    float v = 0.f;
    if (n < NSUB) {
        const float dd = DEN[n];
        if (dd > 0.f) v = NUM[n] / dd;
    }
    #pragma unroll
    for (int o = 32; o; o >>= 1) v += __shfl_xor(v, o);
    if ((threadIdx.x & 63) == 0 && v != 0.f) atomicAdd(out + 1, -v * (1.0f / NSUB));
}

extern "C" void kernel_launch(void* const* d_in, const int* in_sizes, int n_in,
                              void* d_out, int out_size, void* d_ws, size_t ws_size,
                              hipStream_t stream) {
    const float* x    = (const float*)d_in[0];
    const float* Mu   = (const float*)d_in[1];
    const float* Var  = (const float*)d_in[2];
    const int*   ei   = (const int*)d_in[3];
    const int*   sidx = (const int*)d_in[4];
    const float* Wp   = (const float*)d_in[5];
    const float* Sp   = (const float*)d_in[6];
    const float* Wl   = (const float*)d_in[7];
    const float* bl   = (const float*)d_in[8];
    const float* Wr   = (const float*)d_in[9];
    const float* br   = (const float*)d_in[10];
    const float* att  = (const float*)d_in[11];
    float* out = (float*)d_out;
    float* ws  = (float*)d_ws;

    unsigned short* B1 = (unsigned short*)(ws + OFF_B1);
    unsigned short* B2 = (unsigned short*)(ws + OFF_B2);
    float* D    = ws + OFF_D;
    float* SP   = ws + OFF_SP;
    float* DP   = ws + OFF_DP;
    float* NUM  = ws + OFF_NUM;
    float* DEN  = ws + OFF_DEN;

    (void)in_sizes; (void)n_in; (void)out_size; (void)ws_size;

    k_prep<<<112, 256, 0, stream>>>(Mu, Var, Wl, Wr, B1, B2, D, NUM, out);
    k_cell<<<NSUB / 16, 256, 0, stream>>>(x, sidx, Wp, Sp, bl, br, B1, B2, D,
                                          out, SP, DP);
    k_edge<<<(NE + 255) / 256, 256, 0, stream>>>(ei, att, SP, DP, NUM, DEN);
    k_node<<<(NSUB + 255) / 256, 256, 0, stream>>>(NUM, DEN, out);
}

// Round 18
// 39.417 us; speedup vs baseline: 1.9094x; 1.1635x over previous
//
#include <hip/hip_runtime.h>

#define NSUB   10000
#define NCLS   17
#define NG     500
#define NE     80000
#define HIDN   8
#define NEG_SLOPE 0.2f

typedef __attribute__((ext_vector_type(8))) short short8;
typedef __attribute__((ext_vector_type(4))) float f32x4;

// ws layout (float units)
#define OFF_B1   0                        // 512x64 bf16 = 16384 float slots
#define OFF_B2   16384                    // 512x32 bf16 = 8192 float slots
#define OFF_D    (OFF_B2 + 8192)          // 32
#define OFF_SP   (OFF_D + 32)             // NSUB*32: {xl[8], P[17], 0 x7} per node
#define OFF_DP   (OFF_SP + NSUB*32)       // NSUB*32: {xr[8], logP[17], 0 x7} per node
#define OFF_NUM  (OFF_DP + NSUB*32)       // NSUB
#define OFF_DEN  (OFF_NUM + NSUB)         // NSUB
#define OFF_LLP  (OFF_DEN + NSUB)         // 625 per-tile ll partials (plain stores)

__device__ __forceinline__ unsigned short f2bf(float f) {
    unsigned u = __float_as_uint(f);
    u += 0x7FFFu + ((u >> 16) & 1u);      // round-to-nearest-even
    return (unsigned short)(u >> 16);
}

#define MFMA16 __builtin_amdgcn_mfma_f32_16x16x32_bf16

// ---- prep v2 (round-14, measured good): 16-block LDS-staged fragment build ----
__global__ void k_prep(const float* __restrict__ Mu, const float* __restrict__ Var,
                       const float* __restrict__ Wl, const float* __restrict__ Wr,
                       unsigned short* __restrict__ B1, unsigned short* __restrict__ B2,
                       float* __restrict__ D, float* __restrict__ zeroBase,
                       float* __restrict__ out) {
    const int b = blockIdx.x;
    const int tid = threadIdx.x;
    if (b < 16) {
        const int ks = b;
        __shared__ float sMu[NCLS][33], sVa[NCLS][33];
        __shared__ float sWl[32][8], sWr[32][8];
        for (int t = tid; t < NCLS * 32; t += 256) {
            const int c = t >> 5, gg = t & 31;
            const int g = ks * 32 + gg;
            sMu[c][gg] = (g < NG) ? Mu[c * NG + g] : 0.f;
            sVa[c][gg] = (g < NG) ? Var[c * NG + g] : 1.f;
        }
        {
            const int gg = tid >> 3, h = tid & 7;
            const int g = ks * 32 + gg;
            sWl[gg][h] = (g < NG) ? Wl[g * HIDN + h] : 0.f;
            sWr[gg][h] = (g < NG) ? Wr[g * HIDN + h] : 0.f;
        }
        __syncthreads();
        if (tid < 64) {
            const int lane = tid;
            const int fgrp = lane >> 4, fj = lane & 15;
            unsigned short v1[4][8], v2[2][8];
            #pragma unroll
            for (int e = 0; e < 8; e++) {
                const int gg = fgrp * 8 + e;
                const bool gv = (ks * 32 + gg < NG);
                #pragma unroll
                for (int nt = 0; nt < 4; nt++) {
                    const int col = nt * 16 + fj;
                    float v = 0.f;
                    if (gv) {
                        if (col >= 17 && col < 34)      v = sMu[col - 17][gg] / sVa[col - 17][gg];
                        else if (col >= 34 && col < 42) v = sWl[gg][col - 34];
                        else if (col >= 42 && col < 50) v = sWr[gg][col - 42];
                    }
                    v1[nt][e] = f2bf(v);
                }
                #pragma unroll
                for (int nt = 0; nt < 2; nt++) {
                    const int col = nt * 16 + fj;
                    float v = 0.f;
                    if (gv && col < NCLS) v = 1.0f / sVa[col][gg];
                    v2[nt][e] = f2bf(v);
                }
            }
            #pragma unroll
            for (int nt = 0; nt < 4; nt++)
                *reinterpret_cast<short8*>(B1 + (size_t)((ks * 4 + nt) * 64 + lane) * 8) =
                    *reinterpret_cast<short8*>(v1[nt]);
            #pragma unroll
            for (int nt = 0; nt < 2; nt++)
                *reinterpret_cast<short8*>(B2 + (size_t)((ks * 2 + nt) * 64 + lane) * 8) =
                    *reinterpret_cast<short8*>(v2[nt]);
        }
    } else if (b < 33) {
        const int c = b - 16;
        float s = 0.f;
        for (int g = tid; g < NG; g += 256) {
            const float m = Mu[c * NG + g];
            s += m * m / Var[c * NG + g];
        }
        __shared__ float red[4];
        #pragma unroll
        for (int o = 32; o; o >>= 1) s += __shfl_xor(s, o);
        const int w = tid >> 6, l = tid & 63;
        if (l == 0) red[w] = s;
        __syncthreads();
        if (tid == 0) D[c] = red[0] + red[1] + red[2] + red[3];
    } else {
        const int i = (b - 33) * 256 + tid;           // zero NUM/DEN (2*NSUB)
        if (i < 2 * NSUB) zeroBase[i] = 0.f;
        if (b == 33 && tid < 2) out[tid] = 0.f;
    }
}

// ---- per-cell: round-14 GEMM + PARALLEL epilogue (64 lanes) + no hot atomic ----
// Post-GEMM phase rewritten: lane = (replica r = l>>4, cell = l&15); replica r
// handles classes 4r..4r+3 (r==3 also class 16). Cross-replica softmax
// reductions via shfl_xor(16/32) (preserve cell grouping). Serial LDS-read
// chain per lane drops ~190 -> ~40. Per-block ll -> plain store LLPART[bid]
// (625 same-address atomicAdds on out[0] removed; folded in k_node).
__launch_bounds__(256)
__global__ void k_cell(const float* __restrict__ x, const int* __restrict__ sidx,
                       const float* __restrict__ Wp, const float* __restrict__ Sp,
                       const float* __restrict__ blv, const float* __restrict__ brv,
                       const unsigned short* __restrict__ B1,
                       const unsigned short* __restrict__ B2,
                       const float* __restrict__ D,
                       float* __restrict__ out, float* __restrict__ SP,
                       float* __restrict__ DP, float* __restrict__ LLPART) {
    const int tid = threadIdx.x;
    const int w = tid >> 6, l = tid & 63;
    const int grp = l >> 4, j = l & 15;
    const int rowbase = blockIdx.x * 16;             // 625 tiles exactly

    f32x4 a0 = {0,0,0,0}, a1 = {0,0,0,0}, a2 = {0,0,0,0}, a3 = {0,0,0,0};
    const float* xr = x + (size_t)(rowbase + j) * NG;
    const short8* b1 = reinterpret_cast<const short8*>(B1);
    const short8* b2 = reinterpret_cast<const short8*>(B2);

#define KSTEP(ks, fa, fb)                                                \
    {                                                                    \
        const short8* p1 = b1 + (size_t)((ks) * 4) * 64 + l;             \
        const short8* p2 = b2 + (size_t)((ks) * 2) * 64 + l;             \
        a0 = MFMA16(fa, p1[0],   a0, 0, 0, 0);                           \
        a1 = MFMA16(fa, p1[64],  a1, 0, 0, 0);                           \
        a2 = MFMA16(fa, p1[128], a2, 0, 0, 0);                           \
        a3 = MFMA16(fa, p1[192], a3, 0, 0, 0);                           \
        a0 = MFMA16(fb, p2[0],   a0, 0, 0, 0);                           \
        a1 = MFMA16(fb, p2[64],  a1, 0, 0, 0);                           \
    }

    const int ks0 = w * 4;
    #pragma unroll
    for (int i = 0; i < 3; i++) {
        const int ks = ks0 + i;
        const int g0 = ks * 32 + grp * 8;
        const float4 v0 = *reinterpret_cast<const float4*>(xr + g0);
        const float4 v1 = *reinterpret_cast<const float4*>(xr + g0 + 4);
        const float xv[8] = { v0.x, v0.y, v0.z, v0.w, v1.x, v1.y, v1.z, v1.w };
        short8 fa, fb;
        #pragma unroll
        for (int e = 0; e < 8; e++) { fa[e] = (short)f2bf(xv[e]); fb[e] = (short)f2bf(xv[e] * xv[e]); }
        KSTEP(ks, fa, fb);
    }
    if (w < 3) {
        const int ks = ks0 + 3;
        const int g0 = ks * 32 + grp * 8;
        const float4 v0 = *reinterpret_cast<const float4*>(xr + g0);
        const float4 v1 = *reinterpret_cast<const float4*>(xr + g0 + 4);
        const float xv[8] = { v0.x, v0.y, v0.z, v0.w, v1.x, v1.y, v1.z, v1.w };
        short8 fa, fb;
        #pragma unroll
        for (int e = 0; e < 8; e++) { fa[e] = (short)f2bf(xv[e]); fb[e] = (short)f2bf(xv[e] * xv[e]); }
        KSTEP(ks, fa, fb);
    } else {                                         // ks = 15 tail: genes 480..499 valid
        const int g0 = 480 + grp * 8;
        float4 v0 = {0,0,0,0}, v1 = {0,0,0,0};
        if (g0 <= 496) v0 = *reinterpret_cast<const float4*>(xr + g0);
        if (g0 <= 488) v1 = *reinterpret_cast<const float4*>(xr + g0 + 4);
        const float xv[8] = { v0.x, v0.y, v0.z, v0.w, v1.x, v1.y, v1.z, v1.w };
        short8 fa, fb;
        #pragma unroll
        for (int e = 0; e < 8; e++) { fa[e] = (short)f2bf(xv[e]); fb[e] = (short)f2bf(xv[e] * xv[e]); }
        KSTEP(15, fa, fb);
    }
#undef KSTEP

    // C layout: row = grp*4 + r, col = nt*16 + j (m89-verified)
    __shared__ float ct[4][16][68];
    #pragma unroll
    for (int r = 0; r < 4; r++) {
        ct[w][grp * 4 + r][j]      = a0[r];
        ct[w][grp * 4 + r][16 + j] = a1[r];
        ct[w][grp * 4 + r][32 + j] = a2[r];
        ct[w][grp * 4 + r][48 + j] = a3[r];
    }
    __syncthreads();

    if (w == 0) {
        const int cl = l & 15;                        // cell within tile
        const int r  = l >> 4;                        // class-replica 0..3
        const int cell = rowbase + cl;
        const int idx  = sidx[cell];
        const float s  = Sp[idx];
        const float* wrow = Wp + (size_t)idx * NCLS;

        // classes for this replica: c = 4r+k (k=0..3); r==3 also c=16
        float p[4];
        #pragma unroll
        for (int k = 0; k < 4; k++) p[k] = wrow[4 * r + k];
        const float p16raw = (r == 3) ? wrow[16] : -1e30f;

        float mx = fmaxf(fmaxf(p[0], p[1]), fmaxf(p[2], p[3]));
        mx = fmaxf(mx, p16raw);
        mx = fmaxf(mx, __shfl_xor(mx, 16));
        mx = fmaxf(mx, __shfl_xor(mx, 32));

        float sum = 0.f;
        #pragma unroll
        for (int k = 0; k < 4; k++) { p[k] = __expf(p[k] - mx); sum += p[k]; }
        float p16 = (r == 3) ? __expf(p16raw - mx) : 0.f;
        sum += p16;
        sum += __shfl_xor(sum, 16);
        sum += __shfl_xor(sum, 32);
        const float inv = 1.0f / sum;

        float* orow = out + 2 + (size_t)cell * NCLS;
        float* sp   = SP + (size_t)cell * 32;
        float* dp   = DP + (size_t)cell * 32;

        float llp = 0.f;
        #pragma unroll
        for (int k = 0; k < 4; k++) {
            const int c = 4 * r + k;
            p[k] *= inv;
            const float lg = __logf(p[k] + 1e-8f);
            orow[c]   = p[k];
            sp[8 + c] = p[k];
            dp[8 + c] = lg;
            const float T1 = ct[0][cl][c] + ct[1][cl][c] + ct[2][cl][c] + ct[3][cl][c];
            const float T2 = ct[0][cl][NCLS + c] + ct[1][cl][NCLS + c]
                           + ct[2][cl][NCLS + c] + ct[3][cl][NCLS + c];
            llp += p[k] * (-0.5f * T1 + s * T2 - 0.5f * s * s * D[c]);
        }
        if (r == 3) {                                 // class 16
            p16 *= inv;
            const float lg = __logf(p16 + 1e-8f);
            orow[16]   = p16;
            sp[8 + 16] = p16;
            dp[8 + 16] = lg;
            const float T1 = ct[0][cl][16] + ct[1][cl][16] + ct[2][cl][16] + ct[3][cl][16];
            const float T2 = ct[0][cl][NCLS + 16] + ct[1][cl][NCLS + 16]
                           + ct[2][cl][NCLS + 16] + ct[3][cl][NCLS + 16];
            llp += p16 * (-0.5f * T1 + s * T2 - 0.5f * s * s * D[16]);
        }

        // XL/XR: r==1 -> h=k, r==2 -> h=4+k
        if (r == 1 || r == 2) {
            #pragma unroll
            for (int k = 0; k < 4; k++) {
                const int h = (r - 1) * 4 + k;
                sp[h] = ct[0][cl][34 + h] + ct[1][cl][34 + h]
                      + ct[2][cl][34 + h] + ct[3][cl][34 + h] + blv[h];
                dp[h] = ct[0][cl][42 + h] + ct[1][cl][42 + h]
                      + ct[2][cl][42 + h] + ct[3][cl][42 + h] + brv[h];
            }
        }
        // pads 25..31: r==0 -> 25+k (25..28); r==1 -> 29+k for k<3 (29..31)
        if (r == 0) {
            #pragma unroll
            for (int k = 0; k < 4; k++) { sp[25 + k] = 0.f; dp[25 + k] = 0.f; }
        } else if (r == 1) {
            #pragma unroll
            for (int k = 0; k < 3; k++) { sp[29 + k] = 0.f; dp[29 + k] = 0.f; }
        }

        // block ll partial: full-wave reduce, plain store (no same-address atomic)
        float llv = llp;
        #pragma unroll
        for (int o = 32; o; o >>= 1) llv += __shfl_xor(llv, o);
        if (l == 0) LLPART[blockIdx.x] = llv;
    }
}

// ---- fused edge pass: 2-line packed gathers per side, no max-shift ----
__global__ void k_edge(const int* __restrict__ ei, const float* __restrict__ att,
                       const float* __restrict__ SP, const float* __restrict__ DP,
                       float* __restrict__ NUM, float* __restrict__ DEN) {
    const int k = blockIdx.x * 256 + threadIdx.x;
    if (k >= NE) return;
    const int s = ei[k], d = ei[NE + k];
    const float4* sp = reinterpret_cast<const float4*>(SP + (size_t)s * 32);
    const float4* dp = reinterpret_cast<const float4*>(DP + (size_t)d * 32);
    const float4 xa0 = sp[0], xa1 = sp[1];
    const float4 xb0 = dp[0], xb1 = dp[1];
    const float hv[8] = { xa0.x + xb0.x, xa0.y + xb0.y, xa0.z + xb0.z, xa0.w + xb0.w,
                          xa1.x + xb1.x, xa1.y + xb1.y, xa1.z + xb1.z, xa1.w + xb1.w };
    float e = 0.f;
    #pragma unroll
    for (int h = 0; h < HIDN; h++) {
        const float v = hv[h];
        e += ((v > 0.f) ? v : NEG_SLOPE * v) * att[h];
    }
    const float ex = __expf(e);            // no max-shift: |e| <~ 8, exp in f32 range
    float wgt = 0.f;
    #pragma unroll
    for (int q = 2; q < 7; q++) {          // P[17]+pad dot logP[17]+pad
        const float4 ps = sp[q];
        const float4 ld = dp[q];
        wgt += ps.x * ld.x + ps.y * ld.y + ps.z * ld.z + ps.w * ld.w;
    }
    atomicAdd(NUM + d, ex * wgt);
    atomicAdd(DEN + d, ex);
}

// ---- node pass: ce_space sum + LLPART fold ----
__global__ void k_node(const float* __restrict__ NUM, const float* __restrict__ DEN,
                       const float* __restrict__ LLPART, float* __restrict__ out) {
    const int n = blockIdx.x * 256 + threadIdx.x;
    float v = 0.f, vll = 0.f;
    if (n < NSUB) {
        const float dd = DEN[n];
        if (dd > 0.f) v = NUM[n] / dd;
    }
    if (n < 625) vll = LLPART[n];
    #pragma unroll
    for (int o = 32; o; o >>= 1) { v += __shfl_xor(v, o); vll += __shfl_xor(vll, o); }
    if ((threadIdx.x & 63) == 0) {
        if (v != 0.f)   atomicAdd(out + 1, -v * (1.0f / NSUB));
        if (vll != 0.f) atomicAdd(out,     vll * (1.0f / NSUB));
    }
}

extern "C" void kernel_launch(void* const* d_in, const int* in_sizes, int n_in,
                              void* d_out, int out_size, void* d_ws, size_t ws_size,
                              hipStream_t stream) {
    const float* x    = (const float*)d_in[0];
    const float* Mu   = (const float*)d_in[1];
    const float* Var  = (const float*)d_in[2];
    const int*   ei   = (const int*)d_in[3];
    const int*   sidx = (const int*)d_in[4];
    const float* Wp   = (const float*)d_in[5];
    const float* Sp   = (const float*)d_in[6];
    const float* Wl   = (const float*)d_in[7];
    const float* bl   = (const float*)d_in[8];
    const float* Wr   = (const float*)d_in[9];
    const float* br   = (const float*)d_in[10];
    const float* att  = (const float*)d_in[11];
    float* out = (float*)d_out;
    float* ws  = (float*)d_ws;

    unsigned short* B1 = (unsigned short*)(ws + OFF_B1);
    unsigned short* B2 = (unsigned short*)(ws + OFF_B2);
    float* D    = ws + OFF_D;
    float* SP   = ws + OFF_SP;
    float* DP   = ws + OFF_DP;
    float* NUM  = ws + OFF_NUM;
    float* DEN  = ws + OFF_DEN;
    float* LLP  = ws + OFF_LLP;

    (void)in_sizes; (void)n_in; (void)out_size; (void)ws_size;

    k_prep<<<112, 256, 0, stream>>>(Mu, Var, Wl, Wr, B1, B2, D, NUM, out);
    k_cell<<<NSUB / 16, 256, 0, stream>>>(x, sidx, Wp, Sp, bl, br, B1, B2, D,
                                          out, SP, DP, LLP);
    k_edge<<<(NE + 255) / 256, 256, 0, stream>>>(ei, att, SP, DP, NUM, DEN);
    k_node<<<(NSUB + 255) / 256, 256, 0, stream>>>(NUM, DEN, LLP, out);
}